// Round 8
// baseline (321.696 us; speedup 1.0000x reference)
//
#include <hip/hip_runtime.h>

typedef _Float16 f16;
typedef f16 f16x8 __attribute__((ext_vector_type(8)));
typedef float f32x4 __attribute__((ext_vector_type(4)));
typedef unsigned short u16;
typedef unsigned int u32;

#define IN_CH  256
#define HID    256
#define OUT_CH 128
#define LN_EPS 1e-5f
#define NSLOT  32
#define NR     4     // node ranges (LDS-sized histogram privatization)
#define NC     64    // edge chunks (per-chunk copies -> atomic-free fill)
#define RS     12544 // max range size: ceil(50000/4)=12500, padded
#define HT     512   // hist/fill block size

__device__ __forceinline__ float upk_dinv(u32 p) {
    union { u16 u; f16 h; } c; c.u = (u16)(p >> 16); return (float)c.h;
}

// ---------------- hist: packed src(lo16)/dst(hi16) per-range LDS histogram ----------------

__global__ __launch_bounds__(HT) void k_hist(const int* __restrict__ ei, int nE, int nN,
                                             int* __restrict__ hP) {
    __shared__ int h[RS];
    int r = blockIdx.x & (NR - 1), c = blockIdx.x >> 2;
    int rsz = (nN + NR - 1) / NR;
    int r0 = r * rsz;
    int sz = nN - r0; if (sz > rsz) sz = rsz;
    for (int i = threadIdx.x; i < sz; i += HT) h[i] = 0;
    __syncthreads();
    int nT = nE + nN;
    int chunk = (nT + NC - 1) / NC;
    int e0 = c * chunk, e1 = e0 + chunk; if (e1 > nT) e1 = nT;
    for (int eb = e0 + (int)threadIdx.x; eb < e1; eb += HT * 4) {
        int ss[4], dd[4];
        #pragma unroll
        for (int u = 0; u < 4; u++) {
            int e = eb + u * HT;
            ss[u] = -1; dd[u] = -1;
            if (e < e1) {
                if (e < nE) { ss[u] = ei[e]; dd[u] = ei[nE + e]; }
                else { ss[u] = e - nE; dd[u] = e - nE; }
            }
        }
        #pragma unroll
        for (int u = 0; u < 4; u++) {
            if ((unsigned)(ss[u] - r0) < (unsigned)sz) atomicAdd(&h[ss[u] - r0], 1);
            if ((unsigned)(dd[u] - r0) < (unsigned)sz) atomicAdd(&h[dd[u] - r0], 0x10000);
        }
    }
    __syncthreads();
    for (int i = threadIdx.x; i < sz; i += HT) hP[(size_t)c * nN + r0 + i] = h[i];
}

// ---------------- alloc (CSR slice alloc) | cast x->f16 | fragment-major weight prep --------
// Wf layout: element ((ct*8 + kx)*64 + lane)*8 + j  ==  W^T[ct*16 + (lane&15)][kx*32 + (lane>>4)*8 + j]

__global__ __launch_bounds__(256) void k_alloc(const int* __restrict__ hP,
                                               int* __restrict__ rowstart,
                                               int* __restrict__ chunkbase,
                                               int* __restrict__ cnt_tot,
                                               float* __restrict__ dinv,
                                               int* __restrict__ ctr, int nN,
                                               const float* __restrict__ x, f16* __restrict__ xh,
                                               int nelem, int nAllocB, int nCast,
                                               const float* __restrict__ sigw,
                                               const float* __restrict__ c1w,
                                               const float* __restrict__ c2w,
                                               f16* __restrict__ Wt1, f16* __restrict__ Wt2) {
    int bid = blockIdx.x;
    if (bid < nAllocB) {
        int i = bid * 256 + threadIdx.x;
        int lane = threadIdx.x & 63;
        int cnt = 0, dg = 0;
        if (i < nN) {
            for (int c = 0; c < NC; c++) {
                unsigned pk = (unsigned)hP[(size_t)c * nN + i];
                cnt += (int)(pk >> 16);
                dg  += (int)(pk & 0xffffu);
            }
        }
        int p = cnt;
        #pragma unroll
        for (int off = 1; off < 64; off <<= 1) {
            int v = __shfl_up(p, off, 64);
            if (lane >= off) p += v;
        }
        int tot = __shfl(p, 63, 64);
        int base = 0;
        if (lane == 0) base = atomicAdd(ctr, tot);
        base = __shfl(base, 0, 64);
        if (i < nN) {
            int nb = base + p - cnt;
            rowstart[i] = nb;
            cnt_tot[i] = cnt;
            dinv[i] = rsqrtf((float)dg);
            int run = nb;
            for (int c = 0; c < NC; c++) {
                chunkbase[(size_t)c * nN + i] = run;
                run += (int)((unsigned)hP[(size_t)c * nN + i] >> 16);
            }
        }
    } else if (bid < nAllocB + nCast) {
        int i = (bid - nAllocB) * 2048 + threadIdx.x * 8;
        if (i >= nelem) return;
        float4 a = *(const float4*)(x + i);
        float4 b = *(const float4*)(x + i + 4);
        f16x8 o = { (f16)a.x, (f16)a.y, (f16)a.z, (f16)a.w,
                    (f16)b.x, (f16)b.y, (f16)b.z, (f16)b.w };
        *(f16x8*)(xh + i) = o;
    } else {
        int i = (bid - nAllocB - nCast) * 256 + threadIdx.x;   // 0..20479, one f16x8 each
        if (i < 16384) {                  // Wt1: sig half (ct 0..15) | c1 half (ct 16..31)
            int ct = i >> 9;
            int rem = i & 511;
            int kx = rem >> 6;
            int lane = rem & 63;
            int q = lane >> 4, l = lane & 15;
            int n = (ct & 15) * 16 + l;
            int k0 = kx * 32 + q * 8;
            const float* src = (ct < 16) ? sigw : c1w;
            f16x8 o;
            #pragma unroll
            for (int j = 0; j < 8; j++) o[j] = (f16)src[(size_t)(k0 + j) * 256 + n];
            *(f16x8*)(Wt1 + (size_t)i * 8) = o;
        } else {                          // Wt2: ct 0..7
            int h = i - 16384;
            int ct = h >> 9;
            int rem = h & 511;
            int kx = rem >> 6;
            int lane = rem & 63;
            int q = lane >> 4, l = lane & 15;
            int n = ct * 16 + l;
            int k0 = kx * 32 + q * 8;
            f16x8 o;
            #pragma unroll
            for (int j = 0; j < 8; j++) o[j] = (f16)c2w[(size_t)(k0 + j) * 128 + n];
            *(f16x8*)(Wt2 + (size_t)h * 8) = o;
        }
    }
}

// ---------------- fill: counting sort writing packed (dinv_f16 << 16 | src) entries ---------
// dinv gather happens HERE (latency slack), not in the aggregation's critical path.

__global__ __launch_bounds__(HT) void k_fill(const int* __restrict__ ei, int nE, int nN,
                                             const int* __restrict__ chunkbase,
                                             const float* __restrict__ dinv,
                                             u32* __restrict__ sp) {
    __shared__ int pos_[RS];
    int r = blockIdx.x & (NR - 1), c = blockIdx.x >> 2;
    int rsz = (nN + NR - 1) / NR;
    int r0 = r * rsz;
    int sz = nN - r0; if (sz > rsz) sz = rsz;
    for (int i = threadIdx.x; i < sz; i += HT)
        pos_[i] = chunkbase[(size_t)c * nN + r0 + i];
    __syncthreads();
    int nT = nE + nN;
    int chunk = (nT + NC - 1) / NC;
    int e0 = c * chunk, e1 = e0 + chunk; if (e1 > nT) e1 = nT;
    for (int eb = e0 + (int)threadIdx.x; eb < e1; eb += HT * 4) {
        int ss[4], dd[4];
        #pragma unroll
        for (int u = 0; u < 4; u++) {
            int e = eb + u * HT;
            ss[u] = 0; dd[u] = -1;
            if (e < e1) {
                if (e < nE) { ss[u] = ei[e]; dd[u] = ei[nE + e]; }
                else { ss[u] = e - nE; dd[u] = e - nE; }
            }
        }
        float dv[4];
        #pragma unroll
        for (int u = 0; u < 4; u++) dv[u] = (dd[u] >= 0) ? dinv[ss[u]] : 0.f;
        #pragma unroll
        for (int u = 0; u < 4; u++) {
            int l = dd[u] - r0;
            if ((unsigned)l < (unsigned)sz) {
                int pos = atomicAdd(&pos_[l], 1);
                union { f16 h; u16 ub; } cv; cv.h = (f16)dv[u];
                sp[pos] = ((u32)cv.ub << 16) | (u32)(u16)ss[u];
            }
        }
    }
}

// ---------------- AX = dinv_d * sum(dinv_s * xh[src]); packed src+dinv, 8 gathers in flight --

__global__ __launch_bounds__(256) void k_aggX(const f16* __restrict__ xh,
                                              const int* __restrict__ rowstart,
                                              const int* __restrict__ counts,
                                              const u32* __restrict__ sp,
                                              const float* __restrict__ dinv,
                                              f16* __restrict__ AX, int nN) {
    int wv = threadIdx.x >> 6;
    int lane = threadIdx.x & 63;
    int node = blockIdx.x * 4 + wv;
    if (node >= nN) return;
    int h = lane >> 5, sub = lane & 31;
    int beg = rowstart[node];
    int cnt = counts[node];
    float acc0[8] = {}, acc1[8] = {};
    for (int base = 0; base < cnt; base += 64) {
        int el = base + lane;
        u32 pv = 0;
        if (el < cnt) pv = sp[beg + el];
        int rem = cnt - base; if (rem > 64) rem = 64;
        int e = 0;
        for (; e + 16 <= rem; e += 16) {
            u32 p_[8];
            #pragma unroll
            for (int u = 0; u < 8; u++)
                p_[u] = (u32)__shfl((int)pv, e + u * 2 + h, 64);
            f16x8 v_[8];
            #pragma unroll
            for (int u = 0; u < 8; u++)
                v_[u] = *(const f16x8*)(xh + (size_t)(p_[u] & 0xffffu) * 256 + sub * 8);
            #pragma unroll
            for (int u = 0; u < 8; u++) {
                float n = upk_dinv(p_[u]);
                #pragma unroll
                for (int j = 0; j < 8; j++) {
                    float* a = (u & 1) ? acc1 : acc0;
                    a[j] = fmaf(n, (float)v_[u][j], a[j]);
                }
            }
        }
        for (; e < rem; e += 8) {
            int i0 = e + h, i1 = e + 2 + h, i2 = e + 4 + h, i3 = e + 6 + h;
            u32 pa = (u32)__shfl((int)pv, i0, 64), pb = (u32)__shfl((int)pv, i1, 64);
            u32 pc = (u32)__shfl((int)pv, i2, 64), pd = (u32)__shfl((int)pv, i3, 64);
            float na = (i0 < rem) ? upk_dinv(pa) : 0.f;
            float nb = (i1 < rem) ? upk_dinv(pb) : 0.f;
            float nc = (i2 < rem) ? upk_dinv(pc) : 0.f;
            float nd = (i3 < rem) ? upk_dinv(pd) : 0.f;
            f16x8 va = *(const f16x8*)(xh + (size_t)(pa & 0xffffu) * 256 + sub * 8);
            f16x8 vb = *(const f16x8*)(xh + (size_t)(pb & 0xffffu) * 256 + sub * 8);
            f16x8 vc = *(const f16x8*)(xh + (size_t)(pc & 0xffffu) * 256 + sub * 8);
            f16x8 vd = *(const f16x8*)(xh + (size_t)(pd & 0xffffu) * 256 + sub * 8);
            #pragma unroll
            for (int j = 0; j < 8; j++) {
                acc0[j] = fmaf(na, (float)va[j], acc0[j]);
                acc1[j] = fmaf(nb, (float)vb[j], acc1[j]);
                acc0[j] = fmaf(nc, (float)vc[j], acc0[j]);
                acc1[j] = fmaf(nd, (float)vd[j], acc1[j]);
            }
        }
    }
    float dn = dinv[node];
    #pragma unroll
    for (int j = 0; j < 8; j++) {
        acc0[j] += acc1[j];
        acc0[j] += __shfl_xor(acc0[j], 32, 64);
    }
    if (lane < 32) {
        f16x8 o;
        #pragma unroll
        for (int j = 0; j < 8; j++) o[j] = (f16)(acc0[j] * dn);
        *(f16x8*)(AX + (size_t)node * 256 + sub * 8) = o;
    }
}

// ---------------- GEMM(sig): LDS-staged A tile + fragment-major weights ----------------

__global__ __launch_bounds__(256) void k_gemm_sig(const f16* __restrict__ AX,
                                                  const f16* __restrict__ Wt,
                                                  const float* __restrict__ sigb,
                                                  float* __restrict__ sig_part, int M) {
    __shared__ f16 axs[32][256];
    __shared__ f16 tile[32][264];
    f16* axl = &axs[0][0];
    int t = threadIdx.x;
    int w = t >> 6, lane = t & 63, quad = lane >> 4, l16 = lane & 15;
    int m0 = blockIdx.x * 32;
    {
        int tr = t >> 5;           // 0..7
        int c  = t & 31;           // 16B chunk
        #pragma unroll
        for (int p = 0; p < 4; p++) {
            int row = p * 8 + tr;
            int grow = m0 + row; if (grow >= M) grow = M - 1;
            *(f16x8*)(axl + row * 256 + ((c ^ tr) << 3)) =
                *(const f16x8*)(AX + (size_t)grow * 256 + c * 8);
        }
    }
    __syncthreads();
    int cb = w * 64;
    int sw = l16 & 7;
    f32x4 acc[2][4] = {};
    for (int kx = 0; kx < 8; kx++) {
        int c0 = (kx * 4 + quad) ^ sw;
        f16x8 a[2];
        a[0] = *(const f16x8*)(axl + l16 * 256 + (c0 << 3));
        a[1] = *(const f16x8*)(axl + (16 + l16) * 256 + (c0 << 3));
        #pragma unroll
        for (int ns = 0; ns < 4; ns++) {
            int ct = w * 4 + ns;
            f16x8 b = *(const f16x8*)(Wt + ((size_t)((ct * 8 + kx) * 64 + lane) << 3));
            acc[0][ns] = __builtin_amdgcn_mfma_f32_16x16x32_f16(a[0], b, acc[0][ns], 0, 0, 0);
            acc[1][ns] = __builtin_amdgcn_mfma_f32_16x16x32_f16(a[1], b, acc[1][ns], 0, 0, 0);
        }
    }
    #pragma unroll
    for (int ms = 0; ms < 2; ms++)
        #pragma unroll
        for (int ns = 0; ns < 4; ns++)
            #pragma unroll
            for (int r = 0; r < 4; r++) {
                int mr = ms * 16 + quad * 4 + r;
                int c = cb + ns * 16 + l16;
                float v = fmaxf(acc[ms][ns][r] + sigb[c], 0.f);
                if (m0 + mr >= M) v = 0.f;
                tile[mr][c] = (f16)v;
            }
    __syncthreads();
    float s = 0.f;
    #pragma unroll 8
    for (int r = 0; r < 32; r++) s += (float)tile[r][t];
    atomicAdd(&sig_part[(blockIdx.x & (NSLOT - 1)) * 256 + t], s);
}

// ---------------- FC: 12 blocks, wave-per-row coalesced GEMV; pre-combines c1b/c2b ----------------

__global__ __launch_bounds__(256) void k_fc(const float* __restrict__ sig_part,
                                            const float* __restrict__ f1w, const float* __restrict__ f1b,
                                            const float* __restrict__ f2w, const float* __restrict__ f2b,
                                            const float* __restrict__ f3w, const float* __restrict__ f3b,
                                            const float* __restrict__ f4w, const float* __restrict__ f4b,
                                            const float* __restrict__ c1b, const float* __restrict__ c2b,
                                            float* __restrict__ g1, float* __restrict__ bc1,
                                            float* __restrict__ g2, float* __restrict__ bc2) {
    __shared__ float ss[256];
    int t = threadIdx.x;
    float s = 0.f;
    for (int k = 0; k < NSLOT; k++) s += sig_part[k * 256 + t];
    ss[t] = s;
    __syncthreads();
    int wv = t >> 6, lane = t & 63;
    float s0 = ss[lane], s1 = ss[lane + 64], s2v = ss[lane + 128], s3 = ss[lane + 192];
    #pragma unroll
    for (int rr = 0; rr < 16; rr++) {
        int row = blockIdx.x * 64 + wv * 16 + rr;
        const float* w; const float* bb; const float* ex; float* dst; int r;
        if (row < 256)      { w = f1w; bb = f1b; dst = g1;  ex = 0;   r = row; }
        else if (row < 512) { w = f2w; bb = f2b; dst = bc1; ex = c1b; r = row - 256; }
        else if (row < 640) { w = f3w; bb = f3b; dst = g2;  ex = 0;   r = row - 512; }
        else                { w = f4w; bb = f4b; dst = bc2; ex = c2b; r = row - 640; }
        const float* wr = w + (size_t)r * 256;
        float a = wr[lane] * s0;
        a = fmaf(wr[lane + 64], s1, a);
        a = fmaf(wr[lane + 128], s2v, a);
        a = fmaf(wr[lane + 192], s3, a);
        #pragma unroll
        for (int off = 1; off < 64; off <<= 1) a += __shfl_xor(a, off, 64);
        if (lane == 0) dst[r] = tanhf(a + bb[r]) + (ex ? ex[r] : 0.f);
    }
}

// ---------------- fused conv1+FiLM+relu+LN -> f16 LDS -> conv2 -> HW' ----------------

__global__ __launch_bounds__(256) void k_c1f(const f16* __restrict__ AX,
                                             const f16* __restrict__ Wt,   // conv1 frag-major (ct 0..15)
                                             const f16* __restrict__ Wt2,  // conv2 frag-major (ct 0..7)
                                             const float* __restrict__ g1,
                                             const float* __restrict__ bc1, // b1 + c1b precombined
                                             const float* __restrict__ dinv,
                                             f16* __restrict__ HW, int M) {
    __shared__ f16 axs[32][256];
    __shared__ f16 ht[32][264];
    __shared__ float ps[32][5], ps2[32][5];
    __shared__ float mu_[32], rr_[32], sdinv[32];
    f16* axl = &axs[0][0];
    int t = threadIdx.x;
    int w = t >> 6, lane = t & 63, quad = lane >> 4, l16 = lane & 15;
    int m0 = blockIdx.x * 32;
    int cb = w * 64;
    {
        int tr = t >> 5;
        int c  = t & 31;
        #pragma unroll
        for (int p = 0; p < 4; p++) {
            int row = p * 8 + tr;
            int grow = m0 + row; if (grow >= M) grow = M - 1;
            *(f16x8*)(axl + row * 256 + ((c ^ tr) << 3)) =
                *(const f16x8*)(AX + (size_t)grow * 256 + c * 8);
        }
    }
    __syncthreads();
    int sw = l16 & 7;
    f32x4 acc[2][4] = {};
    for (int kx = 0; kx < 8; kx++) {
        int c0 = (kx * 4 + quad) ^ sw;
        f16x8 a[2];
        a[0] = *(const f16x8*)(axl + l16 * 256 + (c0 << 3));
        a[1] = *(const f16x8*)(axl + (16 + l16) * 256 + (c0 << 3));
        #pragma unroll
        for (int ns = 0; ns < 4; ns++) {
            int ct = w * 4 + ns;
            f16x8 b = *(const f16x8*)(Wt + ((size_t)((ct * 8 + kx) * 64 + lane) << 3));
            acc[0][ns] = __builtin_amdgcn_mfma_f32_16x16x32_f16(a[0], b, acc[0][ns], 0, 0, 0);
            acc[1][ns] = __builtin_amdgcn_mfma_f32_16x16x32_f16(a[1], b, acc[1][ns], 0, 0, 0);
        }
    }

    // FiLM + relu in regs; per-row partial LN sums over this lane's 4 cols
    float rs[2][4] = {{0.f,0.f,0.f,0.f},{0.f,0.f,0.f,0.f}};
    float rs2[2][4] = {{0.f,0.f,0.f,0.f},{0.f,0.f,0.f,0.f}};
    #pragma unroll
    for (int ns = 0; ns < 4; ns++) {
        int c = cb + ns * 16 + l16;
        float gv = g1[c], bv = bc1[c];
        #pragma unroll
        for (int ms = 0; ms < 2; ms++)
            #pragma unroll
            for (int r = 0; r < 4; r++) {
                float v = fmaxf(fmaf(gv, acc[ms][ns][r], bv), 0.f);
                acc[ms][ns][r] = v;
                rs[ms][r] += v;
                rs2[ms][r] = fmaf(v, v, rs2[ms][r]);
            }
    }
    #pragma unroll
    for (int off = 1; off < 16; off <<= 1)
        #pragma unroll
        for (int ms = 0; ms < 2; ms++)
            #pragma unroll
            for (int r = 0; r < 4; r++) {
                rs[ms][r]  += __shfl_xor(rs[ms][r], off, 64);
                rs2[ms][r] += __shfl_xor(rs2[ms][r], off, 64);
            }
    if (l16 == 0) {
        #pragma unroll
        for (int ms = 0; ms < 2; ms++)
            #pragma unroll
            for (int r = 0; r < 4; r++) {
                int mr = ms * 16 + quad * 4 + r;
                ps[mr][w] = rs[ms][r];
                ps2[mr][w] = rs2[ms][r];
            }
    }
    __syncthreads();
    if (t < 32) {
        float S = ps[t][0] + ps[t][1] + ps[t][2] + ps[t][3];
        float S2 = ps2[t][0] + ps2[t][1] + ps2[t][2] + ps2[t][3];
        float mu = S * (1.f / 256.f);
        mu_[t] = mu;
        rr_[t] = rsqrtf(S2 * (1.f / 256.f) - mu * mu + LN_EPS);
        int m = m0 + t;
        sdinv[t] = (m < M) ? dinv[m] : 0.f;
    }
    __syncthreads();
    #pragma unroll
    for (int ms = 0; ms < 2; ms++)
        #pragma unroll
        for (int r = 0; r < 4; r++) {
            int mr = ms * 16 + quad * 4 + r;
            float mu = mu_[mr], rr = rr_[mr];
            #pragma unroll
            for (int ns = 0; ns < 4; ns++)
                ht[mr][cb + ns * 16 + l16] = (f16)((acc[ms][ns][r] - mu) * rr);
        }
    __syncthreads();
    int cb2 = w * 32;
    f32x4 acc2[2][2] = {};
    for (int kx = 0; kx < 8; kx++) {
        int ka = kx * 32 + quad * 8;
        f16x8 a[2];
        #pragma unroll
        for (int ms = 0; ms < 2; ms++)
            a[ms] = *(const f16x8*)(&ht[ms * 16 + l16][ka]);
        #pragma unroll
        for (int ns = 0; ns < 2; ns++) {
            int ct = w * 2 + ns;
            f16x8 b = *(const f16x8*)(Wt2 + ((size_t)((ct * 8 + kx) * 64 + lane) << 3));
            acc2[0][ns] = __builtin_amdgcn_mfma_f32_16x16x32_f16(a[0], b, acc2[0][ns], 0, 0, 0);
            acc2[1][ns] = __builtin_amdgcn_mfma_f32_16x16x32_f16(a[1], b, acc2[1][ns], 0, 0, 0);
        }
    }
    #pragma unroll
    for (int ms = 0; ms < 2; ms++)
        #pragma unroll
        for (int ns = 0; ns < 2; ns++)
            #pragma unroll
            for (int r = 0; r < 4; r++) {
                int mr = ms * 16 + quad * 4 + r;
                int m = m0 + mr;
                if (m < M) HW[(size_t)m * 128 + cb2 + ns * 16 + l16] = (f16)(acc2[ms][ns][r] * sdinv[mr]);
            }
}

// ---------------- agg2: out = LN(g2 * dinv_d * sum(HW'[src]) + bc2); 4 gathers in flight ----

__global__ __launch_bounds__(256) void k_agg2(const f16* __restrict__ HW,
                                              const int* __restrict__ rowstart,
                                              const int* __restrict__ counts,
                                              const u32* __restrict__ sp,
                                              const float* __restrict__ dinv,
                                              const float* __restrict__ g2,
                                              const float* __restrict__ bc2,
                                              float* __restrict__ out, int nN) {
    int wv = threadIdx.x >> 6;
    int lane = threadIdx.x & 63;
    int node = blockIdx.x * 4 + wv;
    if (node >= nN) return;
    int q = lane >> 4, sub = lane & 15;
    int beg = rowstart[node];
    int cnt = counts[node];
    float acc0[8] = {}, acc1[8] = {};
    for (int base = 0; base < cnt; base += 64) {
        int el = base + lane;
        int sv = 0; float dv = 0.f;
        if (el < cnt) { sv = (int)(sp[beg + el] & 0xffffu); dv = 1.f; }
        int rem = cnt - base; if (rem > 64) rem = 64;
        int e = 0;
        for (; e + 16 <= rem; e += 16) {
            int s_[4]; float n_[4];
            #pragma unroll
            for (int u = 0; u < 4; u++) {
                int ii = e + u * 4 + q;
                s_[u] = __shfl(sv, ii, 64);
                n_[u] = __shfl(dv, ii, 64);
            }
            f16x8 v_[4];
            #pragma unroll
            for (int u = 0; u < 4; u++)
                v_[u] = *(const f16x8*)(HW + (size_t)s_[u] * 128 + sub * 8);
            #pragma unroll
            for (int u = 0; u < 4; u++)
                #pragma unroll
                for (int j = 0; j < 8; j++) {
                    float* a = (u & 1) ? acc1 : acc0;
                    a[j] = fmaf(n_[u], (float)v_[u][j], a[j]);
                }
        }
        for (; e < rem; e += 8) {
            int i0 = e + q, i1 = e + 4 + q;
            int sa = __shfl(sv, i0, 64), sb = __shfl(sv, i1, 64);
            float na = __shfl(dv, i0, 64), nb = __shfl(dv, i1, 64);
            if (i0 >= rem) na = 0.f;
            if (i1 >= rem) nb = 0.f;
            f16x8 va = *(const f16x8*)(HW + (size_t)sa * 128 + sub * 8);
            f16x8 vb = *(const f16x8*)(HW + (size_t)sb * 128 + sub * 8);
            #pragma unroll
            for (int j = 0; j < 8; j++) {
                acc0[j] = fmaf(na, (float)va[j], acc0[j]);
                acc1[j] = fmaf(nb, (float)vb[j], acc1[j]);
            }
        }
    }
    float dn = dinv[node];
    #pragma unroll
    for (int j = 0; j < 8; j++) {
        acc0[j] += acc1[j];
        acc0[j] += __shfl_xor(acc0[j], 16, 64);
        acc0[j] += __shfl_xor(acc0[j], 32, 64);
    }
    int ch = sub * 8;
    float vfin[8];
    float s = 0.f, s2 = 0.f;
    #pragma unroll
    for (int j = 0; j < 8; j++) {
        float v = fmaf(g2[ch + j], acc0[j] * dn, bc2[ch + j]);
        vfin[j] = v;
        s += v; s2 = fmaf(v, v, s2);
    }
    #pragma unroll
    for (int off = 1; off < 16; off <<= 1) {
        s += __shfl_xor(s, off, 64);
        s2 += __shfl_xor(s2, off, 64);
    }
    float mu = s * (1.f / 128.f);
    float rr = rsqrtf(s2 * (1.f / 128.f) - mu * mu + LN_EPS);
    if (q == 0) {
        float4 o0 = { (vfin[0] - mu) * rr, (vfin[1] - mu) * rr,
                      (vfin[2] - mu) * rr, (vfin[3] - mu) * rr };
        float4 o1 = { (vfin[4] - mu) * rr, (vfin[5] - mu) * rr,
                      (vfin[6] - mu) * rr, (vfin[7] - mu) * rr };
        float* dst = out + (size_t)node * 128 + ch;
        *(float4*)dst = o0;
        *(float4*)(dst + 4) = o1;
    }
}

// ---------------- host launch ----------------

extern "C" void kernel_launch(void* const* d_in, const int* in_sizes, int n_in,
                              void* d_out, int out_size, void* d_ws, size_t ws_size,
                              hipStream_t stream) {
    const float* x    = (const float*)d_in[0];
    const int*   ei   = (const int*)d_in[1];
    const float* c1w  = (const float*)d_in[2];
    const float* c1b  = (const float*)d_in[3];
    const float* c2w  = (const float*)d_in[4];
    const float* c2b  = (const float*)d_in[5];
    const float* sigw = (const float*)d_in[6];
    const float* sigb = (const float*)d_in[7];
    const float* f1w  = (const float*)d_in[8];
    const float* f1b  = (const float*)d_in[9];
    const float* f2w  = (const float*)d_in[10];
    const float* f2b  = (const float*)d_in[11];
    const float* f3w  = (const float*)d_in[12];
    const float* f3b  = (const float*)d_in[13];
    const float* f4w  = (const float*)d_in[14];
    const float* f4b  = (const float*)d_in[15];
    float* out = (float*)d_out;

    int nN = in_sizes[0] / IN_CH;      // 50000
    int nE = in_sizes[1] / 2;          // 800000
    int nT = nE + nN;                  // 850000

    char* base = (char*)d_ws;
    size_t off = 0;
    auto alloc = [&](size_t bytes) { size_t o = off; off += (bytes + 255) & ~(size_t)255; return o; };

    size_t o_spart  = alloc((size_t)NSLOT * 256 * 4);
    size_t o_ctr    = alloc(256);
    size_t zero_bytes = off;                   // zero sig_part/ctr only
    size_t o_hP     = alloc((size_t)NC * nN * 4);
    size_t o_cbase  = alloc((size_t)NC * nN * 4);
    size_t o_g1     = alloc(256 * 4);
    size_t o_b1     = alloc(256 * 4);
    size_t o_g2     = alloc(128 * 4);
    size_t o_b2     = alloc(128 * 4);
    size_t o_rowst  = alloc((size_t)nN * 4);
    size_t o_cntt   = alloc((size_t)nN * 4);
    size_t o_dinv   = alloc((size_t)nN * 4);
    size_t o_src    = alloc((size_t)nT * 4);
    size_t o_wt1    = alloc(512 * 256 * 2);
    size_t o_wt2    = alloc(128 * 256 * 2);
    size_t o_xh     = alloc((size_t)nN * 256 * 2);
    size_t o_AX     = alloc((size_t)nN * 256 * 2);
    size_t o_HW     = alloc((size_t)nN * 128 * 2);

    float* spart  = (float*)(base + o_spart);
    int*   ctr    = (int*)(base + o_ctr);
    int*   hP     = (int*)(base + o_hP);
    int*   cbase  = (int*)(base + o_cbase);
    float* g1     = (float*)(base + o_g1);
    float* bc1    = (float*)(base + o_b1);
    float* g2     = (float*)(base + o_g2);
    float* bc2    = (float*)(base + o_b2);
    int*   rowst  = (int*)(base + o_rowst);
    int*   cntt   = (int*)(base + o_cntt);
    float* dinv   = (float*)(base + o_dinv);
    u32*   sp     = (u32*)(base + o_src);
    f16*   Wt1    = (f16*)(base + o_wt1);
    f16*   Wt2    = (f16*)(base + o_wt2);
    f16*   xh     = (f16*)(base + o_xh);
    f16*   AX     = (f16*)(base + o_AX);
    f16*   HW     = (f16*)(base + o_HW);

    hipMemsetAsync(base, 0, zero_bytes, stream);

    k_hist<<<NR * NC, HT, 0, stream>>>(ei, nE, nN, hP);

    int nAllocB = (nN + 255) / 256;                    // 196
    int nCast = (nN * IN_CH + 2047) / 2048;            // 6250
    int nPrep = (512 * 256 + 128 * 256) / 2048;        // 80 (8 f16 per thread)
    k_alloc<<<nAllocB + nCast + nPrep, 256, 0, stream>>>(hP, rowst, cbase, cntt, dinv, ctr, nN,
                                                         x, xh, nN * IN_CH, nAllocB, nCast,
                                                         sigw, c1w, c2w, Wt1, Wt2);

    k_fill<<<NR * NC, HT, 0, stream>>>(ei, nE, nN, cbase, dinv, sp);

    int nb4 = (nN + 3) / 4;
    int mg = (nN + 31) / 32;
    k_aggX<<<nb4, 256, 0, stream>>>(xh, rowst, cntt, sp, dinv, AX, nN);
    k_gemm_sig<<<mg, 256, 0, stream>>>(AX, Wt1, sigb, spart, nN);
    k_fc<<<12, 256, 0, stream>>>(spart, f1w, f1b, f2w, f2b, f3w, f3b, f4w, f4b,
                                 c1b, c2b, g1, bc1, g2, bc2);
    k_c1f<<<mg, 256, 0, stream>>>(AX, Wt1 + 256 * 256, Wt2, g1, bc1, dinv, HW, nN);
    k_agg2<<<nb4, 256, 0, stream>>>(HW, rowst, cntt, sp, dinv, g2, bc2, out, nN);
}

// Round 9
// 310.279 us; speedup vs baseline: 1.0368x; 1.0368x over previous
//
#include <hip/hip_runtime.h>

typedef _Float16 f16;
typedef f16 f16x8 __attribute__((ext_vector_type(8)));
typedef float f32x4 __attribute__((ext_vector_type(4)));
typedef unsigned short u16;
typedef unsigned int u32;

#define IN_CH  256
#define HID    256
#define OUT_CH 128
#define LN_EPS 1e-5f
#define NSLOT  32
#define NR     8     // node ranges (LDS-sized histogram privatization)
#define NC     32    // edge chunks (per-chunk copies -> atomic-free fill)
#define RS     6272  // max range size: ceil(50000/8)=6250, padded
#define HT     512   // hist/fill block size

// ---------------- hist | cast x->f16 | fragment-major weight prep (one launch) --------------
// hist blocks use 25KB LDS (1-2/CU); cast/prep blocks (no LDS) co-run on the idle wave slots,
// hiding the entire cast stream behind the histogram pass.

__global__ __launch_bounds__(HT) void k_hist(const int* __restrict__ ei, int nE, int nN,
                                             int* __restrict__ hP,
                                             const float* __restrict__ x, f16* __restrict__ xh,
                                             int nelem, int nCast,
                                             const float* __restrict__ sigw,
                                             const float* __restrict__ c1w,
                                             const float* __restrict__ c2w,
                                             f16* __restrict__ Wt1, f16* __restrict__ Wt2) {
    int bid = blockIdx.x;
    if (bid < NR * NC) {
        __shared__ int h[RS];
        int r = bid & (NR - 1), c = bid >> 3;
        int rsz = (nN + NR - 1) / NR;
        int r0 = r * rsz;
        int sz = nN - r0; if (sz > rsz) sz = rsz;
        for (int i = threadIdx.x; i < sz; i += HT) h[i] = 0;
        __syncthreads();
        int nT = nE + nN;
        int chunk = (nT + NC - 1) / NC;
        int e0 = c * chunk, e1 = e0 + chunk; if (e1 > nT) e1 = nT;
        for (int eb = e0 + (int)threadIdx.x; eb < e1; eb += HT * 4) {
            int ss[4], dd[4];
            #pragma unroll
            for (int u = 0; u < 4; u++) {
                int e = eb + u * HT;
                ss[u] = -1; dd[u] = -1;
                if (e < e1) {
                    if (e < nE) { ss[u] = ei[e]; dd[u] = ei[nE + e]; }
                    else { ss[u] = e - nE; dd[u] = e - nE; }
                }
            }
            #pragma unroll
            for (int u = 0; u < 4; u++) {
                if ((unsigned)(ss[u] - r0) < (unsigned)sz) atomicAdd(&h[ss[u] - r0], 1);
                if ((unsigned)(dd[u] - r0) < (unsigned)sz) atomicAdd(&h[dd[u] - r0], 0x10000);
            }
        }
        __syncthreads();
        for (int i = threadIdx.x; i < sz; i += HT) hP[(size_t)c * nN + r0 + i] = h[i];
    } else if (bid < NR * NC + nCast) {
        int i = (bid - NR * NC) * 4096 + threadIdx.x * 8;
        if (i >= nelem) return;
        float4 a = *(const float4*)(x + i);
        float4 b = *(const float4*)(x + i + 4);
        f16x8 o = { (f16)a.x, (f16)a.y, (f16)a.z, (f16)a.w,
                    (f16)b.x, (f16)b.y, (f16)b.z, (f16)b.w };
        *(f16x8*)(xh + i) = o;
    } else {
        int i = (bid - NR * NC - nCast) * HT + threadIdx.x;   // 0..20479, one f16x8 each
        if (i < 16384) {                  // Wt1: sig half (ct 0..15) | c1 half (ct 16..31)
            int ct = i >> 9;
            int rem = i & 511;
            int kx = rem >> 6;
            int lane = rem & 63;
            int q = lane >> 4, l = lane & 15;
            int n = (ct & 15) * 16 + l;
            int k0 = kx * 32 + q * 8;
            const float* src = (ct < 16) ? sigw : c1w;
            f16x8 o;
            #pragma unroll
            for (int j = 0; j < 8; j++) o[j] = (f16)src[(size_t)(k0 + j) * 256 + n];
            *(f16x8*)(Wt1 + (size_t)i * 8) = o;
        } else if (i < 20480) {           // Wt2: ct 0..7
            int h2 = i - 16384;
            int ct = h2 >> 9;
            int rem = h2 & 511;
            int kx = rem >> 6;
            int lane = rem & 63;
            int q = lane >> 4, l = lane & 15;
            int n = ct * 16 + l;
            int k0 = kx * 32 + q * 8;
            f16x8 o;
            #pragma unroll
            for (int j = 0; j < 8; j++) o[j] = (f16)c2w[(size_t)(k0 + j) * 128 + n];
            *(f16x8*)(Wt2 + (size_t)h2 * 8) = o;
        }
    }
}

// ---------------- alloc: CSR slice alloc only (tiny, 196 blocks) ----------------

__global__ __launch_bounds__(256) void k_alloc(const int* __restrict__ hP,
                                               int* __restrict__ rowstart,
                                               int* __restrict__ chunkbase,
                                               int* __restrict__ cnt_tot,
                                               float* __restrict__ dinv,
                                               int* __restrict__ ctr, int nN) {
    int i = blockIdx.x * 256 + threadIdx.x;
    int lane = threadIdx.x & 63;
    int cnt = 0, dg = 0;
    if (i < nN) {
        for (int c = 0; c < NC; c++) {
            unsigned pk = (unsigned)hP[(size_t)c * nN + i];
            cnt += (int)(pk >> 16);
            dg  += (int)(pk & 0xffffu);
        }
    }
    int p = cnt;
    #pragma unroll
    for (int off = 1; off < 64; off <<= 1) {
        int v = __shfl_up(p, off, 64);
        if (lane >= off) p += v;
    }
    int tot = __shfl(p, 63, 64);
    int base = 0;
    if (lane == 0) base = atomicAdd(ctr, tot);
    base = __shfl(base, 0, 64);
    if (i < nN) {
        int nb = base + p - cnt;
        rowstart[i] = nb;
        cnt_tot[i] = cnt;
        dinv[i] = rsqrtf((float)dg);   // deg >= 1 (self loop)
        int run = nb;
        for (int c = 0; c < NC; c++) {
            chunkbase[(size_t)c * nN + i] = run;
            run += (int)((unsigned)hP[(size_t)c * nN + i] >> 16);
        }
    }
}

// ---------------- fill via counting sort: single absolute-position LDS array ----------------

__global__ __launch_bounds__(HT) void k_fill(const int* __restrict__ ei, int nE, int nN,
                                             const int* __restrict__ chunkbase,
                                             u16* __restrict__ src_sorted) {
    __shared__ int pos_[RS];
    int r = blockIdx.x & (NR - 1), c = blockIdx.x >> 3;
    int rsz = (nN + NR - 1) / NR;
    int r0 = r * rsz;
    int sz = nN - r0; if (sz > rsz) sz = rsz;
    for (int i = threadIdx.x; i < sz; i += HT)
        pos_[i] = chunkbase[(size_t)c * nN + r0 + i];
    __syncthreads();
    int nT = nE + nN;
    int chunk = (nT + NC - 1) / NC;
    int e0 = c * chunk, e1 = e0 + chunk; if (e1 > nT) e1 = nT;
    for (int eb = e0 + (int)threadIdx.x; eb < e1; eb += HT * 4) {
        int ss[4], dd[4];
        #pragma unroll
        for (int u = 0; u < 4; u++) {
            int e = eb + u * HT;
            ss[u] = -1; dd[u] = -1;
            if (e < e1) {
                if (e < nE) { ss[u] = ei[e]; dd[u] = ei[nE + e]; }
                else { ss[u] = e - nE; dd[u] = e - nE; }
            }
        }
        #pragma unroll
        for (int u = 0; u < 4; u++) {
            int l = dd[u] - r0;
            if ((unsigned)l < (unsigned)sz) {
                int pos = atomicAdd(&pos_[l], 1);
                src_sorted[pos] = (u16)ss[u];
            }
        }
    }
}

// ---------------- AX = dinv_d * sum(dinv_s * xh[src]); 8 gathers in flight ----------------

__global__ __launch_bounds__(256) void k_aggX(const f16* __restrict__ xh,
                                              const int* __restrict__ rowstart,
                                              const int* __restrict__ counts,
                                              const u16* __restrict__ srcs,
                                              const float* __restrict__ dinv,
                                              f16* __restrict__ AX, int nN) {
    int wv = threadIdx.x >> 6;
    int lane = threadIdx.x & 63;
    int node = blockIdx.x * 4 + wv;
    if (node >= nN) return;
    int h = lane >> 5, sub = lane & 31;
    int beg = rowstart[node];
    int cnt = counts[node];
    float acc0[8] = {}, acc1[8] = {};
    for (int base = 0; base < cnt; base += 64) {
        int el = base + lane;
        int sv = 0; float dv = 0.f;
        if (el < cnt) { sv = srcs[beg + el]; dv = dinv[sv]; }
        int rem = cnt - base; if (rem > 64) rem = 64;
        int e = 0;
        for (; e + 16 <= rem; e += 16) {
            int s_[8]; float n_[8];
            #pragma unroll
            for (int u = 0; u < 8; u++) {
                int ii = e + u * 2 + h;
                s_[u] = __shfl(sv, ii, 64);
                n_[u] = __shfl(dv, ii, 64);
            }
            f16x8 v_[8];
            #pragma unroll
            for (int u = 0; u < 8; u++)
                v_[u] = *(const f16x8*)(xh + (size_t)s_[u] * 256 + sub * 8);
            #pragma unroll
            for (int u = 0; u < 8; u++)
                #pragma unroll
                for (int j = 0; j < 8; j++) {
                    float* a = (u & 1) ? acc1 : acc0;
                    a[j] = fmaf(n_[u], (float)v_[u][j], a[j]);
                }
        }
        for (; e < rem; e += 8) {
            int i0 = e + h, i1 = e + 2 + h, i2 = e + 4 + h, i3 = e + 6 + h;
            int sa = __shfl(sv, i0, 64), sb = __shfl(sv, i1, 64);
            int sc = __shfl(sv, i2, 64), sd = __shfl(sv, i3, 64);
            float na = __shfl(dv, i0, 64), nb = __shfl(dv, i1, 64);
            float nc = __shfl(dv, i2, 64), nd = __shfl(dv, i3, 64);
            if (i0 >= rem) na = 0.f;
            if (i1 >= rem) nb = 0.f;
            if (i2 >= rem) nc = 0.f;
            if (i3 >= rem) nd = 0.f;
            f16x8 va = *(const f16x8*)(xh + (size_t)sa * 256 + sub * 8);
            f16x8 vb = *(const f16x8*)(xh + (size_t)sb * 256 + sub * 8);
            f16x8 vc = *(const f16x8*)(xh + (size_t)sc * 256 + sub * 8);
            f16x8 vd = *(const f16x8*)(xh + (size_t)sd * 256 + sub * 8);
            #pragma unroll
            for (int j = 0; j < 8; j++) {
                acc0[j] = fmaf(na, (float)va[j], acc0[j]);
                acc1[j] = fmaf(nb, (float)vb[j], acc1[j]);
                acc0[j] = fmaf(nc, (float)vc[j], acc0[j]);
                acc1[j] = fmaf(nd, (float)vd[j], acc1[j]);
            }
        }
    }
    float dn = dinv[node];
    #pragma unroll
    for (int j = 0; j < 8; j++) {
        acc0[j] += acc1[j];
        acc0[j] += __shfl_xor(acc0[j], 32, 64);
    }
    if (lane < 32) {
        f16x8 o;
        #pragma unroll
        for (int j = 0; j < 8; j++) o[j] = (f16)(acc0[j] * dn);
        *(f16x8*)(AX + (size_t)node * 256 + sub * 8) = o;
    }
}

// ---------------- GEMM(sig): LDS-staged A tile + fragment-major weights ----------------

__global__ __launch_bounds__(256) void k_gemm_sig(const f16* __restrict__ AX,
                                                  const f16* __restrict__ Wt,
                                                  const float* __restrict__ sigb,
                                                  float* __restrict__ sig_part, int M) {
    __shared__ f16 axs[32][256];
    __shared__ f16 tile[32][264];
    f16* axl = &axs[0][0];
    int t = threadIdx.x;
    int w = t >> 6, lane = t & 63, quad = lane >> 4, l16 = lane & 15;
    int m0 = blockIdx.x * 32;
    {
        int tr = t >> 5;           // 0..7
        int c  = t & 31;           // 16B chunk
        #pragma unroll
        for (int p = 0; p < 4; p++) {
            int row = p * 8 + tr;
            int grow = m0 + row; if (grow >= M) grow = M - 1;
            *(f16x8*)(axl + row * 256 + ((c ^ tr) << 3)) =
                *(const f16x8*)(AX + (size_t)grow * 256 + c * 8);
        }
    }
    __syncthreads();
    int cb = w * 64;
    int sw = l16 & 7;
    f32x4 acc[2][4] = {};
    for (int kx = 0; kx < 8; kx++) {
        int c0 = (kx * 4 + quad) ^ sw;
        f16x8 a[2];
        a[0] = *(const f16x8*)(axl + l16 * 256 + (c0 << 3));
        a[1] = *(const f16x8*)(axl + (16 + l16) * 256 + (c0 << 3));
        #pragma unroll
        for (int ns = 0; ns < 4; ns++) {
            int ct = w * 4 + ns;
            f16x8 b = *(const f16x8*)(Wt + ((size_t)((ct * 8 + kx) * 64 + lane) << 3));
            acc[0][ns] = __builtin_amdgcn_mfma_f32_16x16x32_f16(a[0], b, acc[0][ns], 0, 0, 0);
            acc[1][ns] = __builtin_amdgcn_mfma_f32_16x16x32_f16(a[1], b, acc[1][ns], 0, 0, 0);
        }
    }
    #pragma unroll
    for (int ms = 0; ms < 2; ms++)
        #pragma unroll
        for (int ns = 0; ns < 4; ns++)
            #pragma unroll
            for (int r = 0; r < 4; r++) {
                int mr = ms * 16 + quad * 4 + r;
                int c = cb + ns * 16 + l16;
                float v = fmaxf(acc[ms][ns][r] + sigb[c], 0.f);
                if (m0 + mr >= M) v = 0.f;
                tile[mr][c] = (f16)v;
            }
    __syncthreads();
    float s = 0.f;
    #pragma unroll 8
    for (int r = 0; r < 32; r++) s += (float)tile[r][t];
    atomicAdd(&sig_part[(blockIdx.x & (NSLOT - 1)) * 256 + t], s);
}

// ---------------- FC: 12 blocks, wave-per-row coalesced GEMV; pre-combines c1b/c2b ----------------

__global__ __launch_bounds__(256) void k_fc(const float* __restrict__ sig_part,
                                            const float* __restrict__ f1w, const float* __restrict__ f1b,
                                            const float* __restrict__ f2w, const float* __restrict__ f2b,
                                            const float* __restrict__ f3w, const float* __restrict__ f3b,
                                            const float* __restrict__ f4w, const float* __restrict__ f4b,
                                            const float* __restrict__ c1b, const float* __restrict__ c2b,
                                            float* __restrict__ g1, float* __restrict__ bc1,
                                            float* __restrict__ g2, float* __restrict__ bc2) {
    __shared__ float ss[256];
    int t = threadIdx.x;
    float s = 0.f;
    for (int k = 0; k < NSLOT; k++) s += sig_part[k * 256 + t];
    ss[t] = s;
    __syncthreads();
    int wv = t >> 6, lane = t & 63;
    float s0 = ss[lane], s1 = ss[lane + 64], s2v = ss[lane + 128], s3 = ss[lane + 192];
    #pragma unroll
    for (int rr = 0; rr < 16; rr++) {
        int row = blockIdx.x * 64 + wv * 16 + rr;
        const float* w; const float* bb; const float* ex; float* dst; int r;
        if (row < 256)      { w = f1w; bb = f1b; dst = g1;  ex = 0;   r = row; }
        else if (row < 512) { w = f2w; bb = f2b; dst = bc1; ex = c1b; r = row - 256; }
        else if (row < 640) { w = f3w; bb = f3b; dst = g2;  ex = 0;   r = row - 512; }
        else                { w = f4w; bb = f4b; dst = bc2; ex = c2b; r = row - 640; }
        const float* wr = w + (size_t)r * 256;
        float a = wr[lane] * s0;
        a = fmaf(wr[lane + 64], s1, a);
        a = fmaf(wr[lane + 128], s2v, a);
        a = fmaf(wr[lane + 192], s3, a);
        #pragma unroll
        for (int off = 1; off < 64; off <<= 1) a += __shfl_xor(a, off, 64);
        if (lane == 0) dst[r] = tanhf(a + bb[r]) + (ex ? ex[r] : 0.f);
    }
}

// ---------------- fused conv1+FiLM+relu+LN -> f16 LDS -> conv2 -> HW' ----------------

__global__ __launch_bounds__(256) void k_c1f(const f16* __restrict__ AX,
                                             const f16* __restrict__ Wt,   // conv1 frag-major (ct 0..15)
                                             const f16* __restrict__ Wt2,  // conv2 frag-major (ct 0..7)
                                             const float* __restrict__ g1,
                                             const float* __restrict__ bc1, // b1 + c1b precombined
                                             const float* __restrict__ dinv,
                                             f16* __restrict__ HW, int M) {
    __shared__ f16 axs[32][256];
    __shared__ f16 ht[32][264];
    __shared__ float ps[32][5], ps2[32][5];
    __shared__ float mu_[32], rr_[32], sdinv[32];
    f16* axl = &axs[0][0];
    int t = threadIdx.x;
    int w = t >> 6, lane = t & 63, quad = lane >> 4, l16 = lane & 15;
    int m0 = blockIdx.x * 32;
    int cb = w * 64;
    {
        int tr = t >> 5;
        int c  = t & 31;
        #pragma unroll
        for (int p = 0; p < 4; p++) {
            int row = p * 8 + tr;
            int grow = m0 + row; if (grow >= M) grow = M - 1;
            *(f16x8*)(axl + row * 256 + ((c ^ tr) << 3)) =
                *(const f16x8*)(AX + (size_t)grow * 256 + c * 8);
        }
    }
    __syncthreads();
    int sw = l16 & 7;
    f32x4 acc[2][4] = {};
    for (int kx = 0; kx < 8; kx++) {
        int c0 = (kx * 4 + quad) ^ sw;
        f16x8 a[2];
        a[0] = *(const f16x8*)(axl + l16 * 256 + (c0 << 3));
        a[1] = *(const f16x8*)(axl + (16 + l16) * 256 + (c0 << 3));
        #pragma unroll
        for (int ns = 0; ns < 4; ns++) {
            int ct = w * 4 + ns;
            f16x8 b = *(const f16x8*)(Wt + ((size_t)((ct * 8 + kx) * 64 + lane) << 3));
            acc[0][ns] = __builtin_amdgcn_mfma_f32_16x16x32_f16(a[0], b, acc[0][ns], 0, 0, 0);
            acc[1][ns] = __builtin_amdgcn_mfma_f32_16x16x32_f16(a[1], b, acc[1][ns], 0, 0, 0);
        }
    }

    // FiLM + relu in regs; per-row partial LN sums over this lane's 4 cols
    float rs[2][4] = {{0.f,0.f,0.f,0.f},{0.f,0.f,0.f,0.f}};
    float rs2[2][4] = {{0.f,0.f,0.f,0.f},{0.f,0.f,0.f,0.f}};
    #pragma unroll
    for (int ns = 0; ns < 4; ns++) {
        int c = cb + ns * 16 + l16;
        float gv = g1[c], bv = bc1[c];
        #pragma unroll
        for (int ms = 0; ms < 2; ms++)
            #pragma unroll
            for (int r = 0; r < 4; r++) {
                float v = fmaxf(fmaf(gv, acc[ms][ns][r], bv), 0.f);
                acc[ms][ns][r] = v;
                rs[ms][r] += v;
                rs2[ms][r] = fmaf(v, v, rs2[ms][r]);
            }
    }
    #pragma unroll
    for (int off = 1; off < 16; off <<= 1)
        #pragma unroll
        for (int ms = 0; ms < 2; ms++)
            #pragma unroll
            for (int r = 0; r < 4; r++) {
                rs[ms][r]  += __shfl_xor(rs[ms][r], off, 64);
                rs2[ms][r] += __shfl_xor(rs2[ms][r], off, 64);
            }
    if (l16 == 0) {
        #pragma unroll
        for (int ms = 0; ms < 2; ms++)
            #pragma unroll
            for (int r = 0; r < 4; r++) {
                int mr = ms * 16 + quad * 4 + r;
                ps[mr][w] = rs[ms][r];
                ps2[mr][w] = rs2[ms][r];
            }
    }
    __syncthreads();
    if (t < 32) {
        float S = ps[t][0] + ps[t][1] + ps[t][2] + ps[t][3];
        float S2 = ps2[t][0] + ps2[t][1] + ps2[t][2] + ps2[t][3];
        float mu = S * (1.f / 256.f);
        mu_[t] = mu;
        rr_[t] = rsqrtf(S2 * (1.f / 256.f) - mu * mu + LN_EPS);
        int m = m0 + t;
        sdinv[t] = (m < M) ? dinv[m] : 0.f;
    }
    __syncthreads();
    #pragma unroll
    for (int ms = 0; ms < 2; ms++)
        #pragma unroll
        for (int r = 0; r < 4; r++) {
            int mr = ms * 16 + quad * 4 + r;
            float mu = mu_[mr], rr = rr_[mr];
            #pragma unroll
            for (int ns = 0; ns < 4; ns++)
                ht[mr][cb + ns * 16 + l16] = (f16)((acc[ms][ns][r] - mu) * rr);
        }
    __syncthreads();
    int cb2 = w * 32;
    f32x4 acc2[2][2] = {};
    for (int kx = 0; kx < 8; kx++) {
        int ka = kx * 32 + quad * 8;
        f16x8 a[2];
        #pragma unroll
        for (int ms = 0; ms < 2; ms++)
            a[ms] = *(const f16x8*)(&ht[ms * 16 + l16][ka]);
        #pragma unroll
        for (int ns = 0; ns < 2; ns++) {
            int ct = w * 2 + ns;
            f16x8 b = *(const f16x8*)(Wt2 + ((size_t)((ct * 8 + kx) * 64 + lane) << 3));
            acc2[0][ns] = __builtin_amdgcn_mfma_f32_16x16x32_f16(a[0], b, acc2[0][ns], 0, 0, 0);
            acc2[1][ns] = __builtin_amdgcn_mfma_f32_16x16x32_f16(a[1], b, acc2[1][ns], 0, 0, 0);
        }
    }
    #pragma unroll
    for (int ms = 0; ms < 2; ms++)
        #pragma unroll
        for (int ns = 0; ns < 2; ns++)
            #pragma unroll
            for (int r = 0; r < 4; r++) {
                int mr = ms * 16 + quad * 4 + r;
                int m = m0 + mr;
                if (m < M) HW[(size_t)m * 128 + cb2 + ns * 16 + l16] = (f16)(acc2[ms][ns][r] * sdinv[mr]);
            }
}

// ---------------- agg2: out = LN(g2 * dinv_d * sum(HW'[src]) + bc2); 4 gathers in flight ----

__global__ __launch_bounds__(256) void k_agg2(const f16* __restrict__ HW,
                                              const int* __restrict__ rowstart,
                                              const int* __restrict__ counts,
                                              const u16* __restrict__ srcs,
                                              const float* __restrict__ dinv,
                                              const float* __restrict__ g2,
                                              const float* __restrict__ bc2,
                                              float* __restrict__ out, int nN) {
    int wv = threadIdx.x >> 6;
    int lane = threadIdx.x & 63;
    int node = blockIdx.x * 4 + wv;
    if (node >= nN) return;
    int q = lane >> 4, sub = lane & 15;
    int beg = rowstart[node];
    int cnt = counts[node];
    float acc0[8] = {}, acc1[8] = {};
    for (int base = 0; base < cnt; base += 64) {
        int el = base + lane;
        int sv = 0; float dv = 0.f;
        if (el < cnt) { sv = srcs[beg + el]; dv = 1.f; }
        int rem = cnt - base; if (rem > 64) rem = 64;
        int e = 0;
        for (; e + 16 <= rem; e += 16) {
            int s_[4]; float n_[4];
            #pragma unroll
            for (int u = 0; u < 4; u++) {
                int ii = e + u * 4 + q;
                s_[u] = __shfl(sv, ii, 64);
                n_[u] = __shfl(dv, ii, 64);
            }
            f16x8 v_[4];
            #pragma unroll
            for (int u = 0; u < 4; u++)
                v_[u] = *(const f16x8*)(HW + (size_t)s_[u] * 128 + sub * 8);
            #pragma unroll
            for (int u = 0; u < 4; u++)
                #pragma unroll
                for (int j = 0; j < 8; j++) {
                    float* a = (u & 1) ? acc1 : acc0;
                    a[j] = fmaf(n_[u], (float)v_[u][j], a[j]);
                }
        }
        for (; e < rem; e += 8) {
            int i0 = e + q, i1 = e + 4 + q;
            int sa = __shfl(sv, i0, 64), sb = __shfl(sv, i1, 64);
            float na = __shfl(dv, i0, 64), nb = __shfl(dv, i1, 64);
            if (i0 >= rem) na = 0.f;
            if (i1 >= rem) nb = 0.f;
            f16x8 va = *(const f16x8*)(HW + (size_t)sa * 128 + sub * 8);
            f16x8 vb = *(const f16x8*)(HW + (size_t)sb * 128 + sub * 8);
            #pragma unroll
            for (int j = 0; j < 8; j++) {
                acc0[j] = fmaf(na, (float)va[j], acc0[j]);
                acc1[j] = fmaf(nb, (float)vb[j], acc1[j]);
            }
        }
    }
    float dn = dinv[node];
    #pragma unroll
    for (int j = 0; j < 8; j++) {
        acc0[j] += acc1[j];
        acc0[j] += __shfl_xor(acc0[j], 16, 64);
        acc0[j] += __shfl_xor(acc0[j], 32, 64);
    }
    int ch = sub * 8;
    float vfin[8];
    float s = 0.f, s2 = 0.f;
    #pragma unroll
    for (int j = 0; j < 8; j++) {
        float v = fmaf(g2[ch + j], acc0[j] * dn, bc2[ch + j]);
        vfin[j] = v;
        s += v; s2 = fmaf(v, v, s2);
    }
    #pragma unroll
    for (int off = 1; off < 16; off <<= 1) {
        s += __shfl_xor(s, off, 64);
        s2 += __shfl_xor(s2, off, 64);
    }
    float mu = s * (1.f / 128.f);
    float rr = rsqrtf(s2 * (1.f / 128.f) - mu * mu + LN_EPS);
    if (q == 0) {
        float4 o0 = { (vfin[0] - mu) * rr, (vfin[1] - mu) * rr,
                      (vfin[2] - mu) * rr, (vfin[3] - mu) * rr };
        float4 o1 = { (vfin[4] - mu) * rr, (vfin[5] - mu) * rr,
                      (vfin[6] - mu) * rr, (vfin[7] - mu) * rr };
        float* dst = out + (size_t)node * 128 + ch;
        *(float4*)dst = o0;
        *(float4*)(dst + 4) = o1;
    }
}

// ---------------- host launch ----------------

extern "C" void kernel_launch(void* const* d_in, const int* in_sizes, int n_in,
                              void* d_out, int out_size, void* d_ws, size_t ws_size,
                              hipStream_t stream) {
    const float* x    = (const float*)d_in[0];
    const int*   ei   = (const int*)d_in[1];
    const float* c1w  = (const float*)d_in[2];
    const float* c1b  = (const float*)d_in[3];
    const float* c2w  = (const float*)d_in[4];
    const float* c2b  = (const float*)d_in[5];
    const float* sigw = (const float*)d_in[6];
    const float* sigb = (const float*)d_in[7];
    const float* f1w  = (const float*)d_in[8];
    const float* f1b  = (const float*)d_in[9];
    const float* f2w  = (const float*)d_in[10];
    const float* f2b  = (const float*)d_in[11];
    const float* f3w  = (const float*)d_in[12];
    const float* f3b  = (const float*)d_in[13];
    const float* f4w  = (const float*)d_in[14];
    const float* f4b  = (const float*)d_in[15];
    float* out = (float*)d_out;

    int nN = in_sizes[0] / IN_CH;      // 50000
    int nE = in_sizes[1] / 2;          // 800000
    int nT = nE + nN;                  // 850000

    char* base = (char*)d_ws;
    size_t off = 0;
    auto alloc = [&](size_t bytes) { size_t o = off; off += (bytes + 255) & ~(size_t)255; return o; };

    size_t o_spart  = alloc((size_t)NSLOT * 256 * 4);
    size_t o_ctr    = alloc(256);
    size_t zero_bytes = off;                   // zero sig_part/ctr only
    size_t o_hP     = alloc((size_t)NC * nN * 4);
    size_t o_cbase  = alloc((size_t)NC * nN * 4);
    size_t o_g1     = alloc(256 * 4);
    size_t o_b1     = alloc(256 * 4);
    size_t o_g2     = alloc(128 * 4);
    size_t o_b2     = alloc(128 * 4);
    size_t o_rowst  = alloc((size_t)nN * 4);
    size_t o_cntt   = alloc((size_t)nN * 4);
    size_t o_dinv   = alloc((size_t)nN * 4);
    size_t o_src    = alloc((size_t)nT * 2);
    size_t o_wt1    = alloc(512 * 256 * 2);
    size_t o_wt2    = alloc(128 * 256 * 2);
    size_t o_xh     = alloc((size_t)nN * 256 * 2);
    size_t o_AX     = alloc((size_t)nN * 256 * 2);
    size_t o_HW     = alloc((size_t)nN * 128 * 2);

    float* spart  = (float*)(base + o_spart);
    int*   ctr    = (int*)(base + o_ctr);
    int*   hP     = (int*)(base + o_hP);
    int*   cbase  = (int*)(base + o_cbase);
    float* g1     = (float*)(base + o_g1);
    float* bc1    = (float*)(base + o_b1);
    float* g2     = (float*)(base + o_g2);
    float* bc2    = (float*)(base + o_b2);
    int*   rowst  = (int*)(base + o_rowst);
    int*   cntt   = (int*)(base + o_cntt);
    float* dinv   = (float*)(base + o_dinv);
    u16*   srcs   = (u16*)(base + o_src);
    f16*   Wt1    = (f16*)(base + o_wt1);
    f16*   Wt2    = (f16*)(base + o_wt2);
    f16*   xh     = (f16*)(base + o_xh);
    f16*   AX     = (f16*)(base + o_AX);
    f16*   HW     = (f16*)(base + o_HW);

    hipMemsetAsync(base, 0, zero_bytes, stream);

    int nCast = (nN * IN_CH + 4095) / 4096;            // 3125 (512 thr x 8 elems)
    int nPrep = (20480 + HT - 1) / HT;                 // 40
    k_hist<<<NR * NC + nCast + nPrep, HT, 0, stream>>>(ei, nE, nN, hP,
                                                       x, xh, nN * IN_CH, nCast,
                                                       sigw, c1w, c2w, Wt1, Wt2);

    k_alloc<<<(nN + 255) / 256, 256, 0, stream>>>(hP, rowst, cbase, cntt, dinv, ctr, nN);

    k_fill<<<NR * NC, HT, 0, stream>>>(ei, nE, nN, cbase, srcs);

    int nb4 = (nN + 3) / 4;
    int mg = (nN + 31) / 32;
    k_aggX<<<nb4, 256, 0, stream>>>(xh, rowst, cntt, srcs, dinv, AX, nN);
    k_gemm_sig<<<mg, 256, 0, stream>>>(AX, Wt1, sigb, spart, nN);
    k_fc<<<12, 256, 0, stream>>>(spart, f1w, f1b, f2w, f2b, f3w, f3b, f4w, f4b,
                                 c1b, c2b, g1, bc1, g2, bc2);
    k_c1f<<<mg, 256, 0, stream>>>(AX, Wt1 + 256 * 256, Wt2, g1, bc1, dinv, HW, nN);
    k_agg2<<<nb4, 256, 0, stream>>>(HW, rowst, cntt, srcs, dinv, g2, bc2, out, nN);
}